// Round 10
// baseline (160.075 us; speedup 1.0000x reference)
//
#include <hip/hip_runtime.h>

// Problem constants
constexpr int GG    = 512;          // graphs
constexpr int NPG   = 128;          // nodes per graph
constexpr int FIN   = 64;
constexpr int DD    = 128;
constexpr int RR    = 4;
constexpr int NN    = GG * NPG;     // 65536 nodes
constexpr int EE    = 1572864;      // edges
constexpr int SLC   = 4096;         // per-graph record slice (avg 3072, sd ~55)
constexpr int HSTR  = 136;          // hG padded row stride in u16 (17 granules: odd -> conflict-free)
constexpr int BPAD  = 32;           // bcur counter stride in u32 (128 B: 1 counter/line)

typedef __attribute__((ext_vector_type(8))) _Float16 f16x8;
typedef __attribute__((ext_vector_type(2))) _Float16 f16x2;
typedef __attribute__((ext_vector_type(4))) float f32x4;
typedef unsigned short u16;
typedef unsigned int   u32;

__device__ __forceinline__ u16 f16b(float x) {
    _Float16 h = (_Float16)x;
    return __builtin_bit_cast(u16, h);
}
__device__ __forceinline__ f16x2 as2(u32 w) { return __builtin_bit_cast(f16x2, w); }

// async global->LDS DMA, 16 B per lane; LDS side must be uniform-base + lane*16
__device__ __forceinline__ void gl_lds16(const void* g, void* l) {
    __builtin_amdgcn_global_load_lds((const __attribute__((address_space(1))) u32*)g,
                                     (__attribute__((address_space(3))) u32*)l, 16, 0, 0);
}

// ---------------- front: binA + prep (r22 version, verbatim) -----------------
// Ledger: 384-block binA is the best of 3 tested shapes (768 regressed ~4us,
// persistent-fold deadlocked). Do not touch without new counter evidence.

__global__ __launch_bounds__(256, 2) void k_front(const int* __restrict__ ei,
                                                  const int* __restrict__ ea,
                                                  u32* __restrict__ bcur,
                                                  u16* __restrict__ binned,
                                                  const float* __restrict__ W_root,
                                                  const float* __restrict__ W_rel,
                                                  const float* __restrict__ W_emb,
                                                  u16* __restrict__ wtH) {
    __shared__ u32 sRec[4096];                 // 16 KB staged rec|bucket (binA)
    __shared__ int bh[512];                    // per-graph counts
    __shared__ int lcur[512];                  // local scatter cursor
    __shared__ int lstart[512];                // local run starts (kept for write-out)
    __shared__ int gbase[512];                 // global run bases (reserved)
    __shared__ int wt4[4];                     // per-wave scan totals
    __shared__ float tile[32 * 129];           // 16.5 KB transpose tile (prep) / sorted recs (binA)
    int tid = threadIdx.x;
    int bid = blockIdx.x;

    if (bid < 384) {
        // ---- binA: LDS histogram -> in-LDS counting sort -> coalesced out ----
        // rec = locSrc(7) | loc(7)<<7 | rel(2)<<14 (edges are within-graph)
        int e0 = bid * 4096;                   // 384 blocks cover EE exactly
        bh[tid] = 0; bh[tid + 256] = 0;
        __syncthreads();
        for (int i = 0; i < 16; ++i) {
            int e = e0 + i * 256 + tid;
            int src = ei[e];
            int dst = ei[EE + e];
            int a   = ea[e];
            int g   = dst >> 7;                // graph id = bucket
            u32 rec = (u32)(src & 127) | ((u32)(dst & 127) << 7) | ((u32)a << 14);
            sRec[i * 256 + tid] = rec | ((u32)g << 16);
            atomicAdd(&bh[g], 1);
        }
        __syncthreads();
        // thread t owns buckets 2t, 2t+1 (bucket order preserved across waves)
        int c0 = bh[2 * tid], c1 = bh[2 * tid + 1];
        int s  = c0 + c1;
        int v  = s;                            // intra-wave inclusive scan of pairs
        int lane = tid & 63, wv = tid >> 6;
#pragma unroll
        for (int o = 1; o < 64; o <<= 1) {
            int t = __shfl_up(v, o);
            if (lane >= o) v += t;
        }
        if (lane == 63) wt4[wv] = v;
        // global reservation (padded counters; latency hidden to next barrier)
        gbase[2 * tid]     = (2 * tid) * SLC +
                             (int)atomicAdd(&bcur[(2 * tid) * BPAD], (u32)c0);
        gbase[2 * tid + 1] = (2 * tid + 1) * SLC +
                             (int)atomicAdd(&bcur[(2 * tid + 1) * BPAD], (u32)c1);
        __syncthreads();
        int base = 0;
#pragma unroll
        for (int w = 0; w < 4; ++w)
            if (w < wv) base += wt4[w];
        int ex = base + v - s;                 // exclusive start of bucket 2t
        lstart[2 * tid]     = ex;
        lstart[2 * tid + 1] = ex + c0;
        lcur[2 * tid]       = ex;
        lcur[2 * tid + 1]   = ex + c0;
        __syncthreads();
        u32* sorted = (u32*)tile;              // tile dead in this branch
        for (int i = 0; i < 16; ++i) {         // rank-scatter into LDS
            u32 r = sRec[i * 256 + tid];
            int pos = atomicAdd(&lcur[r >> 16], 1);
            sorted[pos] = r;
        }
        __syncthreads();
        for (int i = 0; i < 16; ++i) {         // coalesced run write-out
            int p = i * 256 + tid;
            u32 r = sorted[p];
            int g = r >> 16;
            binned[gbase[g] + (p - lstart[g])] = (u16)(r & 0xFFFFu);
        }
    } else if (bid < 424) {
        // ---- prep layer mats: 4 blocks/mat, 32 k-rows x 128 n per block ----
        int pb = bid - 384;                    // 0..39
        int mat = pb >> 2;                     // 0..9
        int k0 = (pb & 3) * 32;
        int l = mat / 5, m5 = mat - l * 5;
        const float* Wsrc = (m5 == 0) ? (W_root + l * 16384)
                                      : (W_rel + (size_t)(l * RR + (m5 - 1)) * 16384);
        for (int i = 0; i < 16; ++i) {         // coalesced read (n fastest)
            int k = k0 + (tid >> 7) + i * 2;
            int n = tid & 127;
            tile[(k - k0) * 129 + n] = Wsrc[k * 128 + n];
        }
        __syncthreads();
        for (int i = 0; i < 16; ++i) {         // coalesced write (k fastest)
            int kk = tid & 31;
            int n  = (tid >> 5) + i * 8;
            wtH[mat * 16384 + n * 128 + k0 + kk] = f16b(tile[kk * 129 + n]);
        }
    } else {
        // ---- prep wtE = W_emb^T (128 n x 64 k) at +163840, 2 blocks ----
        int k0 = (bid - 424) * 32;
        for (int i = 0; i < 16; ++i) {
            int k = k0 + (tid >> 7) + i * 2;
            int n = tid & 127;
            tile[(k - k0) * 129 + n] = W_emb[k * 128 + n];
        }
        __syncthreads();
        for (int i = 0; i < 16; ++i) {
            int kk = tid & 31;
            int n  = (tid >> 5) + i * 8;
            wtH[163840 + n * 64 + k0 + kk] = f16b(tile[kk * 129 + n]);
        }
    }
}

// ---------------- fused sort + embed + two-layer RGCN + max-pool -------------
// One block per graph, 512 threads = 8 waves; wave owns a 16-node M-strip.
// r30 (drain-cover attack, on top of r29 = r22 + setprio, best 159.9 us):
// __syncthreads drains vmcnt(0); the h1-step DMA previously had only its own
// 16-MFMA span to fly before the drain, while gather (barrier-free) ran AFTER
// the drain. Reorder: gather(m) now sits between h1's MFMAs and the barrier,
// so the next half-mat's DMA flies under the whole gather. The L0 epilogue
// hG-write and L1 max-pool reduce similarly merge into mat4's h1 pre-barrier
// slot (2 barriers deleted). Buffer safety unchanged: every stage still lands
// one full barrier before its reader; hG has no readers after mat3's barrier.
// Dead ends (measured): B-from-L2 (r24/r25), graph-pairing (r28), hG swizzle
// (r27), front resharding (r26), persistent fold (r23).

__global__ __launch_bounds__(512, 4) void k_fused(const float* __restrict__ x,
                                                  const float* __restrict__ b_emb,
                                                  float* __restrict__ outF,
                                                  const u16* __restrict__ wtH,
                                                  const float* __restrict__ bias,
                                                  const u16* __restrict__ binned,
                                                  const u32* __restrict__ bcur) {
    __shared__ __align__(16) u16 hG[128 * HSTR];   // 34816 B current-layer h (f16)
    __shared__ __align__(16) u16 sQ[2][8192];      // 32768 B B half-mat dbuf
    __shared__ __align__(16) u16 sIdx[SLC];        //  8192 B sorted src (alias: wtot, red)
    __shared__ int   sOffs[512];                   //  2048 B segment starts
    __shared__ int   sCnt[512];                    //  2048 B hist / cursor / seg ENDS
    __shared__ float sInv[512];                    //  2048 B inverse counts
                                                   //  total 81920 B exactly

    int tid  = threadIdx.x;
    int wave = tid >> 6, lane = tid & 63;
    int mm   = lane & 15;            // MFMA m/n lane == gather node index
    int qd   = lane >> 4;            // MFMA quad == gather col-chunk selector
    int gr   = blockIdx.x;           // graph id
    int row0g = gr * NPG;            // global row base
    int strip = wave * 16;           // local node base of this wave
    const u16* wtE = wtH + 163840;   // embed matrix (128 n x 64 k)

    // stage half-mat `step` (mat step>>1, k-half step&1) into sQ[bufi].
    // 1024 granules; slot(n, j) = n*8 + (j ^ (n&7)), j = ks*4 + quad.
    auto stage = [&](int step, int bufi) {
        const u16* src = wtH + (step >> 1) * 16384 + (step & 1) * 64;
#pragma unroll
        for (int i = 0; i < 2; ++i) {
            int u = i * 512 + tid;
            int n = u >> 3, j = u & 7;
            gl_lds16(src + n * 128 + ((j ^ (n & 7)) * 8), &sQ[bufi][u * 8]);
        }
    };
    // stage embed matrix (K=64 -> exactly one 16 KB half-buffer)
    auto stageE = [&](int bufi) {
#pragma unroll
        for (int i = 0; i < 2; ++i) {
            int u = i * 512 + tid;
            int n = u >> 3, j = u & 7;
            gl_lds16(wtE + n * 64 + ((j ^ (n & 7)) * 8), &sQ[bufi][u * 8]);
        }
    };

    f32x4 acc[8];
    // one k-half: 16 B-frag reads + 16 MFMAs. slot(n, j) with j = ks*4 + qd
    auto mfma_half = [&](int bufi, f16x8 A0, f16x8 A1) {
        const u16* buf = sQ[bufi];
        __builtin_amdgcn_s_setprio(1);           // favor MFMA-issuing wave (T5)
#pragma unroll
        for (int nt = 0; nt < 8; ++nt) {
            int n = nt * 16 + mm;
            int g0 = n * 8 + ((0 * 4 + qd) ^ (n & 7));
            int g1 = n * 8 + ((1 * 4 + qd) ^ (n & 7));
            f16x8 B0 = *(const f16x8*)&buf[g0 * 8];
            f16x8 B1 = *(const f16x8*)&buf[g1 * 8];
            f32x4 a = acc[nt];
            a = __builtin_amdgcn_mfma_f32_16x16x32_f16(A0, B0, a, 0, 0, 0);
            a = __builtin_amdgcn_mfma_f32_16x16x32_f16(A1, B1, a, 0, 0, 0);
            acc[nt] = a;
        }
        __builtin_amdgcn_s_setprio(0);
    };

    // A-layout-direct mean-aggregate, single pass over full 128-col rows.
    // Lane (mm,qd) covers cols q*32 + qd*8 + 0..7 for q = 0..3; each uint4 word
    // is two f16 columns -> one v_pk_add_f16. No unpack, no repack.
    auto gather = [&](int rel, f16x8* AH) {
        int key = (rel << 7) + strip + mm;
        int r0 = sOffs[key];
        int r1 = sCnt[key];                      // post-scatter cursor == segment end
        _Float16 hs = (_Float16)sInv[key];
        f16x2 sv; sv[0] = hs; sv[1] = hs;
        int cb = qd * 8;
        f16x2 ax[16];
#pragma unroll
        for (int i = 0; i < 16; ++i) ax[i] = (f16x2){(_Float16)0.f, (_Float16)0.f};
        auto add8 = [&](int ks, uint4 u) {
            ax[ks * 4 + 0] += as2(u.x);
            ax[ks * 4 + 1] += as2(u.y);
            ax[ks * 4 + 2] += as2(u.z);
            ax[ks * 4 + 3] += as2(u.w);
        };
        int j = r0;
        for (; j + 2 <= r1; j += 2) {            // 2 edges -> 8 reads in flight
            int rb0 = (int)sIdx[j]     * HSTR + cb;
            int rb1 = (int)sIdx[j + 1] * HSTR + cb;
            uint4 a0 = *(const uint4*)&hG[rb0];
            uint4 a1 = *(const uint4*)&hG[rb0 + 32];
            uint4 a2 = *(const uint4*)&hG[rb0 + 64];
            uint4 a3 = *(const uint4*)&hG[rb0 + 96];
            uint4 b0 = *(const uint4*)&hG[rb1];
            uint4 b1 = *(const uint4*)&hG[rb1 + 32];
            uint4 b2 = *(const uint4*)&hG[rb1 + 64];
            uint4 b3 = *(const uint4*)&hG[rb1 + 96];
            add8(0, a0); add8(1, a1); add8(2, a2); add8(3, a3);
            add8(0, b0); add8(1, b1); add8(2, b2); add8(3, b3);
        }
        if (j < r1) {
            int rb = (int)sIdx[j] * HSTR + cb;
            uint4 a0 = *(const uint4*)&hG[rb];
            uint4 a1 = *(const uint4*)&hG[rb + 32];
            uint4 a2 = *(const uint4*)&hG[rb + 64];
            uint4 a3 = *(const uint4*)&hG[rb + 96];
            add8(0, a0); add8(1, a1); add8(2, a2); add8(3, a3);
        }
#pragma unroll
        for (int q = 0; q < 4; ++q) {            // mean scale -> A-frag, in reg
            union { u32 w[4]; f16x8 v; } o;
#pragma unroll
            for (int t = 0; t < 4; ++t) {
                f16x2 r = ax[q * 4 + t] * sv;
                o.w[t] = __builtin_bit_cast(u32, r);
            }
            AH[q] = o.v;
        }
    };

    // ---- prologue: in-LDS counting sort (shuffle-scan prefix) ----
    stageE(0);                                   // embed DMA into buf0
    int cnt = (int)bcur[gr * BPAD];
    if (cnt > SLC) cnt = SLC;                    // never in practice (18 sigma)
    uint4 myRec = *(const uint4*)&binned[gr * SLC + tid * 8];   // 8 recs/thread
    sCnt[tid] = 0;
    __syncthreads();
    int base8 = tid * 8;
#pragma unroll
    for (int i = 0; i < 8; ++i) {
        if (base8 + i < cnt) {
            u32 w = ((const u32*)&myRec)[i >> 1];
            u32 rec = (i & 1) ? (w >> 16) : (w & 0xFFFFu);
            atomicAdd(&sCnt[rec >> 7], 1);
        }
    }
    __syncthreads();
    int c = sCnt[tid];
    int v = c;                                   // intra-wave inclusive scan
#pragma unroll
    for (int o = 1; o < 64; o <<= 1) {
        int t = __shfl_up(v, o);
        if (lane >= o) v += t;
    }
    int* wtot = (int*)sIdx;                      // sort-phase scratch (sIdx dead)
    if (lane == 63) wtot[wave] = v;
    __syncthreads();
    int base = 0;
#pragma unroll
    for (int w = 0; w < 8; ++w) {
        int tw = wtot[w];
        if (w < wave) base += tw;
    }
    int ex = base + v - c;
    sOffs[tid] = ex;
    sCnt[tid]  = ex;                             // rank cursor -> becomes seg END
    sInv[tid]  = 1.0f / (float)(c > 0 ? c : 1);
    __syncthreads();
#pragma unroll
    for (int i = 0; i < 8; ++i) {                // rank-scatter local src indices
        if (base8 + i < cnt) {
            u32 w = ((const u32*)&myRec)[i >> 1];
            u32 rec = (i & 1) ? (w >> 16) : (w & 0xFFFFu);
            int pos = atomicAdd(&sCnt[rec >> 7], 1);
            sIdx[pos] = (u16)(rec & 127u);
        }
    }
    __syncthreads();                             // sort done; embed buf0 drained

    // ---- embed: hG = f16(x @ W_emb + b_emb), A from global x ----
    {
#pragma unroll
        for (int nt = 0; nt < 8; ++nt) {
            float bv = b_emb[nt * 16 + mm];
            acc[nt] = (f32x4){bv, bv, bv, bv};
        }
        f16x8 AE[2];
#pragma unroll
        for (int ks = 0; ks < 2; ++ks) {         // k = ks*32 + qd*8 + 0..7
            const float* xp = &x[(size_t)(row0g + strip + mm) * FIN + ks * 32 + qd * 8];
            float4 a = *(const float4*)xp;
            float4 b = *(const float4*)(xp + 4);
            union { u32 w[4]; f16x8 v; } o;
            o.w[0] = (u32)f16b(a.x) | ((u32)f16b(a.y) << 16);
            o.w[1] = (u32)f16b(a.z) | ((u32)f16b(a.w) << 16);
            o.w[2] = (u32)f16b(b.x) | ((u32)f16b(b.y) << 16);
            o.w[3] = (u32)f16b(b.z) | ((u32)f16b(b.w) << 16);
            AE[ks] = o.v;
        }
        stage(0, 1);                             // L0 mat0 half0 -> buf1
        mfma_half(0, AE[0], AE[1]);
#pragma unroll
        for (int nt = 0; nt < 8; ++nt)           // write h0 rows into hG (no relu)
#pragma unroll
            for (int r = 0; r < 4; ++r)
                hG[(strip + qd * 4 + r) * HSTR + nt * 16 + mm] =
                    f16b(acc[nt][r]);
        __syncthreads();                         // hG visible; buf1 DMA drained (under hG write)
    }

    // ---- two layers x 5 matrices, 2 half-steps each ----
    for (int L = 0; L < 2; ++L) {
        const float* bl = bias + L * DD;
#pragma unroll
        for (int i = 0; i < 8; ++i) acc[i] = (f32x4){0.f, 0.f, 0.f, 0.f};

        f16x8 AH[4];
#pragma unroll
        for (int ks = 0; ks < 4; ++ks)           // root A direct from hG
            AH[ks] = *(const f16x8*)&hG[(strip + mm) * HSTR + ks * 32 + qd * 8];

        for (int m = 0; m < 5; ++m) {
            int s0 = L * 10 + m * 2;
            // ---- h = 0 ----
            stage(s0 + 1, s0 & 1);
            mfma_half((s0 + 1) & 1, AH[0], AH[1]);
            __syncthreads();                     // buf(s0&1) drained; buf((s0+1)&1) free
            // ---- h = 1 ----
            int s1 = s0 + 1;
            if (s1 + 1 < 20) stage(s1 + 1, s1 & 1);
            mfma_half((s1 + 1) & 1, AH[2], AH[3]);
            if (m < 4) {
                gather(m, AH);                   // next mat's A; covers s1+1 DMA
                __syncthreads();                 // drain flew under gather
            }
            // m == 4: barrier merged into the epilogue below
        }

        if (L == 0) {
            // epilogue write BEFORE the barrier: covers stage(10)'s DMA drain.
            // Safe: last hG readers (gather(3), root-A) finished before mat3's
            // post-gather barrier; epilogue touches only this wave's acc.
#pragma unroll
            for (int nt = 0; nt < 8; ++nt) {
                float bv = bl[nt * 16 + mm];
#pragma unroll
                for (int r = 0; r < 4; ++r)
                    hG[(strip + qd * 4 + r) * HSTR + nt * 16 + mm] =
                        f16b(fmaxf(acc[nt][r] + bv, 0.f));
            }
            __syncthreads();                     // h1 visible; L1 mat0 DMA drained
        } else {
            // max-pool: per-wave column max -> LDS (red overlays dead sIdx) -> store
            float* red = (float*)sIdx;
#pragma unroll
            for (int nt = 0; nt < 8; ++nt) {
                float bv = bl[nt * 16 + mm];
                float vv = fmaxf(fmaxf(acc[nt][0], acc[nt][1]),
                                 fmaxf(acc[nt][2], acc[nt][3])) + bv;
                vv = fmaxf(vv, 0.f);             // relu(max) == max(relu)
                vv = fmaxf(vv, __shfl_xor(vv, 16));
                vv = fmaxf(vv, __shfl_xor(vv, 32));
                if (lane < 16) red[wave * 128 + nt * 16 + mm] = vv;
            }
            __syncthreads();                     // merged: mat4-h1 + reduce barrier
            if (tid < 128) {
                float mx = red[tid];
#pragma unroll
                for (int w = 1; w < 8; ++w) mx = fmaxf(mx, red[w * 128 + tid]);
                outF[gr * DD + tid] = mx;
            }
        }
    }
}

// ---------------- launch ----------------

extern "C" void kernel_launch(void* const* d_in, const int* in_sizes, int n_in,
                              void* d_out, int out_size, void* d_ws, size_t ws_size,
                              hipStream_t stream) {
    const float* x      = (const float*)d_in[0];
    const int*   ei     = (const int*)  d_in[1];
    const int*   ea     = (const int*)  d_in[2];
    const float* W_emb  = (const float*)d_in[3];
    const float* b_emb  = (const float*)d_in[4];
    const float* W_root = (const float*)d_in[5];
    const float* W_rel  = (const float*)d_in[6];
    const float* bias   = (const float*)d_in[7];
    float* out = (float*)d_out;

    char* p = (char*)d_ws;
    u32* bcur   = (u32*)p; p += (size_t)512 * BPAD * 4;             // padded cursors (memset 0)
    u16* binned = (u16*)p; p += (size_t)GG * SLC * 2;               // 4.19 MB static slices
    u16* wtH    = (u16*)p; p += (size_t)(10 * 16384 + 8192) * 2;    // 0.35 MB (+wtE)

    (void)hipMemsetAsync(bcur, 0, (size_t)512 * BPAD * 4, stream);

    k_front<<<426, 256, 0, stream>>>(ei, ea, bcur, binned,
                                     W_root, W_rel, W_emb, wtH);
    k_fused<<<GG, 512, 0, stream>>>(x, b_emb, out, wtH, bias, binned, bcur);
}

// Round 11
// 159.159 us; speedup vs baseline: 1.0058x; 1.0058x over previous
//
#include <hip/hip_runtime.h>

// Problem constants
constexpr int GG    = 512;          // graphs
constexpr int NPG   = 128;          // nodes per graph
constexpr int FIN   = 64;
constexpr int DD    = 128;
constexpr int RR    = 4;
constexpr int NN    = GG * NPG;     // 65536 nodes
constexpr int EE    = 1572864;      // edges
constexpr int SLC   = 4096;         // per-graph record slice (avg 3072, sd ~55)
constexpr int HSTR  = 136;          // hG padded row stride in u16 (17 granules: odd -> conflict-free)
constexpr int BPAD  = 32;           // bcur counter stride in u32 (128 B: 1 counter/line)

typedef __attribute__((ext_vector_type(8))) _Float16 f16x8;
typedef __attribute__((ext_vector_type(2))) _Float16 f16x2;
typedef __attribute__((ext_vector_type(4))) float f32x4;
typedef unsigned short u16;
typedef unsigned int   u32;

__device__ __forceinline__ u16 f16b(float x) {
    _Float16 h = (_Float16)x;
    return __builtin_bit_cast(u16, h);
}
__device__ __forceinline__ f16x2 as2(u32 w) { return __builtin_bit_cast(f16x2, w); }

// async global->LDS DMA, 16 B per lane; LDS side must be uniform-base + lane*16
__device__ __forceinline__ void gl_lds16(const void* g, void* l) {
    __builtin_amdgcn_global_load_lds((const __attribute__((address_space(1))) u32*)g,
                                     (__attribute__((address_space(3))) u32*)l, 16, 0, 0);
}

// ---------------- front: binA + prep (r22 version, verbatim) -----------------
// Ledger: 384-block binA is the best of 3 tested shapes (768 regressed ~4us,
// persistent-fold deadlocked). Do not touch without new counter evidence.

__global__ __launch_bounds__(256, 2) void k_front(const int* __restrict__ ei,
                                                  const int* __restrict__ ea,
                                                  u32* __restrict__ bcur,
                                                  u16* __restrict__ binned,
                                                  const float* __restrict__ W_root,
                                                  const float* __restrict__ W_rel,
                                                  const float* __restrict__ W_emb,
                                                  u16* __restrict__ wtH) {
    __shared__ u32 sRec[4096];                 // 16 KB staged rec|bucket (binA)
    __shared__ int bh[512];                    // per-graph counts
    __shared__ int lcur[512];                  // local scatter cursor
    __shared__ int lstart[512];                // local run starts (kept for write-out)
    __shared__ int gbase[512];                 // global run bases (reserved)
    __shared__ int wt4[4];                     // per-wave scan totals
    __shared__ float tile[32 * 129];           // 16.5 KB transpose tile (prep) / sorted recs (binA)
    int tid = threadIdx.x;
    int bid = blockIdx.x;

    if (bid < 384) {
        // ---- binA: LDS histogram -> in-LDS counting sort -> coalesced out ----
        // rec = locSrc(7) | loc(7)<<7 | rel(2)<<14 (edges are within-graph)
        int e0 = bid * 4096;                   // 384 blocks cover EE exactly
        bh[tid] = 0; bh[tid + 256] = 0;
        __syncthreads();
        for (int i = 0; i < 16; ++i) {
            int e = e0 + i * 256 + tid;
            int src = ei[e];
            int dst = ei[EE + e];
            int a   = ea[e];
            int g   = dst >> 7;                // graph id = bucket
            u32 rec = (u32)(src & 127) | ((u32)(dst & 127) << 7) | ((u32)a << 14);
            sRec[i * 256 + tid] = rec | ((u32)g << 16);
            atomicAdd(&bh[g], 1);
        }
        __syncthreads();
        // thread t owns buckets 2t, 2t+1 (bucket order preserved across waves)
        int c0 = bh[2 * tid], c1 = bh[2 * tid + 1];
        int s  = c0 + c1;
        int v  = s;                            // intra-wave inclusive scan of pairs
        int lane = tid & 63, wv = tid >> 6;
#pragma unroll
        for (int o = 1; o < 64; o <<= 1) {
            int t = __shfl_up(v, o);
            if (lane >= o) v += t;
        }
        if (lane == 63) wt4[wv] = v;
        // global reservation (padded counters; latency hidden to next barrier)
        gbase[2 * tid]     = (2 * tid) * SLC +
                             (int)atomicAdd(&bcur[(2 * tid) * BPAD], (u32)c0);
        gbase[2 * tid + 1] = (2 * tid + 1) * SLC +
                             (int)atomicAdd(&bcur[(2 * tid + 1) * BPAD], (u32)c1);
        __syncthreads();
        int base = 0;
#pragma unroll
        for (int w = 0; w < 4; ++w)
            if (w < wv) base += wt4[w];
        int ex = base + v - s;                 // exclusive start of bucket 2t
        lstart[2 * tid]     = ex;
        lstart[2 * tid + 1] = ex + c0;
        lcur[2 * tid]       = ex;
        lcur[2 * tid + 1]   = ex + c0;
        __syncthreads();
        u32* sorted = (u32*)tile;              // tile dead in this branch
        for (int i = 0; i < 16; ++i) {         // rank-scatter into LDS
            u32 r = sRec[i * 256 + tid];
            int pos = atomicAdd(&lcur[r >> 16], 1);
            sorted[pos] = r;
        }
        __syncthreads();
        for (int i = 0; i < 16; ++i) {         // coalesced run write-out
            int p = i * 256 + tid;
            u32 r = sorted[p];
            int g = r >> 16;
            binned[gbase[g] + (p - lstart[g])] = (u16)(r & 0xFFFFu);
        }
    } else if (bid < 424) {
        // ---- prep layer mats: 4 blocks/mat, 32 k-rows x 128 n per block ----
        int pb = bid - 384;                    // 0..39
        int mat = pb >> 2;                     // 0..9
        int k0 = (pb & 3) * 32;
        int l = mat / 5, m5 = mat - l * 5;
        const float* Wsrc = (m5 == 0) ? (W_root + l * 16384)
                                      : (W_rel + (size_t)(l * RR + (m5 - 1)) * 16384);
        for (int i = 0; i < 16; ++i) {         // coalesced read (n fastest)
            int k = k0 + (tid >> 7) + i * 2;
            int n = tid & 127;
            tile[(k - k0) * 129 + n] = Wsrc[k * 128 + n];
        }
        __syncthreads();
        for (int i = 0; i < 16; ++i) {         // coalesced write (k fastest)
            int kk = tid & 31;
            int n  = (tid >> 5) + i * 8;
            wtH[mat * 16384 + n * 128 + k0 + kk] = f16b(tile[kk * 129 + n]);
        }
    } else {
        // ---- prep wtE = W_emb^T (128 n x 64 k) at +163840, 2 blocks ----
        int k0 = (bid - 424) * 32;
        for (int i = 0; i < 16; ++i) {
            int k = k0 + (tid >> 7) + i * 2;
            int n = tid & 127;
            tile[(k - k0) * 129 + n] = W_emb[k * 128 + n];
        }
        __syncthreads();
        for (int i = 0; i < 16; ++i) {
            int kk = tid & 31;
            int n  = (tid >> 5) + i * 8;
            wtH[163840 + n * 64 + k0 + kk] = f16b(tile[kk * 129 + n]);
        }
    }
}

// ---------------- fused sort + embed + two-layer RGCN + max-pool -------------
// One block per graph, 512 threads = 8 waves; wave owns a 16-node M-strip.
// r31 = r29 verbatim (best measured: 159.94 us total, k_fused 65.7).
// Structure: r22 DMA-staged half-mat double-buffer + T5 setprio around MFMA
// clusters (+2-3%, role-diverse 2-blocks/CU regime).
// Measured dead ends (do not retry without new counter evidence):
//   - B-from-L1/L2 instead of LDS (r24/r25): vmem-latency-bound, MfmaUtil 5.5%
//   - graph-pairing 1024t/1 block/CU (r28): barrier coupling + spill, +18 us
//   - hG granule XOR-swizzle (r27): conflicts are inherent 64-lane->8-slot
//     b128 row-gather aliasing; counter flat, VALU cost +8 pts
//   - persistent-kernel grid barrier (r23): dispatch-order unsafe, 30 ms spin
//   - front resharding 768 blocks (r26): 2x global atomics, -4 us residual
//   - drain-cover barrier reorder (r30): null; 2-block TLP already hides DMA
// Structural floor arithmetic: ~65 us fixed harness overhead (r23 single-
// kernel measurement) + ~28 us front+gap (4-way invariant) + ~66 us fused
// (~42 us LDS-port: B 2.7 MB + gather 1.6 MB per block @ ~85 B/cy, 2 blk/CU;
// 8x B re-read inherent to M-split; N-split spills; conflicts inherent).

__global__ __launch_bounds__(512, 4) void k_fused(const float* __restrict__ x,
                                                  const float* __restrict__ b_emb,
                                                  float* __restrict__ outF,
                                                  const u16* __restrict__ wtH,
                                                  const float* __restrict__ bias,
                                                  const u16* __restrict__ binned,
                                                  const u32* __restrict__ bcur) {
    __shared__ __align__(16) u16 hG[128 * HSTR];   // 34816 B current-layer h (f16)
    __shared__ __align__(16) u16 sQ[2][8192];      // 32768 B B half-mat dbuf
    __shared__ __align__(16) u16 sIdx[SLC];        //  8192 B sorted src (alias: wtot, red)
    __shared__ int   sOffs[512];                   //  2048 B segment starts
    __shared__ int   sCnt[512];                    //  2048 B hist / cursor / seg ENDS
    __shared__ float sInv[512];                    //  2048 B inverse counts
                                                   //  total 81920 B exactly

    int tid  = threadIdx.x;
    int wave = tid >> 6, lane = tid & 63;
    int mm   = lane & 15;            // MFMA m/n lane == gather node index
    int qd   = lane >> 4;            // MFMA quad == gather col-chunk selector
    int gr   = blockIdx.x;           // graph id
    int row0g = gr * NPG;            // global row base
    int strip = wave * 16;           // local node base of this wave
    const u16* wtE = wtH + 163840;   // embed matrix (128 n x 64 k)

    // stage half-mat `step` (mat step>>1, k-half step&1) into sQ[bufi].
    // 1024 granules; slot(n, j) = n*8 + (j ^ (n&7)), j = ks*4 + quad.
    auto stage = [&](int step, int bufi) {
        const u16* src = wtH + (step >> 1) * 16384 + (step & 1) * 64;
#pragma unroll
        for (int i = 0; i < 2; ++i) {
            int u = i * 512 + tid;
            int n = u >> 3, j = u & 7;
            gl_lds16(src + n * 128 + ((j ^ (n & 7)) * 8), &sQ[bufi][u * 8]);
        }
    };
    // stage embed matrix (K=64 -> exactly one 16 KB half-buffer)
    auto stageE = [&](int bufi) {
#pragma unroll
        for (int i = 0; i < 2; ++i) {
            int u = i * 512 + tid;
            int n = u >> 3, j = u & 7;
            gl_lds16(wtE + n * 64 + ((j ^ (n & 7)) * 8), &sQ[bufi][u * 8]);
        }
    };

    f32x4 acc[8];
    // one k-half: 16 B-frag reads + 16 MFMAs. slot(n, j) with j = ks*4 + qd
    auto mfma_half = [&](int bufi, f16x8 A0, f16x8 A1) {
        const u16* buf = sQ[bufi];
        __builtin_amdgcn_s_setprio(1);           // favor MFMA-issuing wave (T5)
#pragma unroll
        for (int nt = 0; nt < 8; ++nt) {
            int n = nt * 16 + mm;
            int g0 = n * 8 + ((0 * 4 + qd) ^ (n & 7));
            int g1 = n * 8 + ((1 * 4 + qd) ^ (n & 7));
            f16x8 B0 = *(const f16x8*)&buf[g0 * 8];
            f16x8 B1 = *(const f16x8*)&buf[g1 * 8];
            f32x4 a = acc[nt];
            a = __builtin_amdgcn_mfma_f32_16x16x32_f16(A0, B0, a, 0, 0, 0);
            a = __builtin_amdgcn_mfma_f32_16x16x32_f16(A1, B1, a, 0, 0, 0);
            acc[nt] = a;
        }
        __builtin_amdgcn_s_setprio(0);
    };

    // A-layout-direct mean-aggregate, single pass over full 128-col rows.
    // Lane (mm,qd) covers cols q*32 + qd*8 + 0..7 for q = 0..3; each uint4 word
    // is two f16 columns -> one v_pk_add_f16. No unpack, no repack.
    auto gather = [&](int rel, f16x8* AH) {
        int key = (rel << 7) + strip + mm;
        int r0 = sOffs[key];
        int r1 = sCnt[key];                      // post-scatter cursor == segment end
        _Float16 hs = (_Float16)sInv[key];
        f16x2 sv; sv[0] = hs; sv[1] = hs;
        int cb = qd * 8;
        f16x2 ax[16];
#pragma unroll
        for (int i = 0; i < 16; ++i) ax[i] = (f16x2){(_Float16)0.f, (_Float16)0.f};
        auto add8 = [&](int ks, uint4 u) {
            ax[ks * 4 + 0] += as2(u.x);
            ax[ks * 4 + 1] += as2(u.y);
            ax[ks * 4 + 2] += as2(u.z);
            ax[ks * 4 + 3] += as2(u.w);
        };
        int j = r0;
        for (; j + 2 <= r1; j += 2) {            // 2 edges -> 8 reads in flight
            int rb0 = (int)sIdx[j]     * HSTR + cb;
            int rb1 = (int)sIdx[j + 1] * HSTR + cb;
            uint4 a0 = *(const uint4*)&hG[rb0];
            uint4 a1 = *(const uint4*)&hG[rb0 + 32];
            uint4 a2 = *(const uint4*)&hG[rb0 + 64];
            uint4 a3 = *(const uint4*)&hG[rb0 + 96];
            uint4 b0 = *(const uint4*)&hG[rb1];
            uint4 b1 = *(const uint4*)&hG[rb1 + 32];
            uint4 b2 = *(const uint4*)&hG[rb1 + 64];
            uint4 b3 = *(const uint4*)&hG[rb1 + 96];
            add8(0, a0); add8(1, a1); add8(2, a2); add8(3, a3);
            add8(0, b0); add8(1, b1); add8(2, b2); add8(3, b3);
        }
        if (j < r1) {
            int rb = (int)sIdx[j] * HSTR + cb;
            uint4 a0 = *(const uint4*)&hG[rb];
            uint4 a1 = *(const uint4*)&hG[rb + 32];
            uint4 a2 = *(const uint4*)&hG[rb + 64];
            uint4 a3 = *(const uint4*)&hG[rb + 96];
            add8(0, a0); add8(1, a1); add8(2, a2); add8(3, a3);
        }
#pragma unroll
        for (int q = 0; q < 4; ++q) {            // mean scale -> A-frag, in reg
            union { u32 w[4]; f16x8 v; } o;
#pragma unroll
            for (int t = 0; t < 4; ++t) {
                f16x2 r = ax[q * 4 + t] * sv;
                o.w[t] = __builtin_bit_cast(u32, r);
            }
            AH[q] = o.v;
        }
    };

    // ---- prologue: in-LDS counting sort (shuffle-scan prefix) ----
    stageE(0);                                   // embed DMA into buf0
    int cnt = (int)bcur[gr * BPAD];
    if (cnt > SLC) cnt = SLC;                    // never in practice (18 sigma)
    uint4 myRec = *(const uint4*)&binned[gr * SLC + tid * 8];   // 8 recs/thread
    sCnt[tid] = 0;
    __syncthreads();
    int base8 = tid * 8;
#pragma unroll
    for (int i = 0; i < 8; ++i) {
        if (base8 + i < cnt) {
            u32 w = ((const u32*)&myRec)[i >> 1];
            u32 rec = (i & 1) ? (w >> 16) : (w & 0xFFFFu);
            atomicAdd(&sCnt[rec >> 7], 1);
        }
    }
    __syncthreads();
    int c = sCnt[tid];
    int v = c;                                   // intra-wave inclusive scan
#pragma unroll
    for (int o = 1; o < 64; o <<= 1) {
        int t = __shfl_up(v, o);
        if (lane >= o) v += t;
    }
    int* wtot = (int*)sIdx;                      // sort-phase scratch (sIdx dead)
    if (lane == 63) wtot[wave] = v;
    __syncthreads();
    int base = 0;
#pragma unroll
    for (int w = 0; w < 8; ++w) {
        int tw = wtot[w];
        if (w < wave) base += tw;
    }
    int ex = base + v - c;
    sOffs[tid] = ex;
    sCnt[tid]  = ex;                             // rank cursor -> becomes seg END
    sInv[tid]  = 1.0f / (float)(c > 0 ? c : 1);
    __syncthreads();
#pragma unroll
    for (int i = 0; i < 8; ++i) {                // rank-scatter local src indices
        if (base8 + i < cnt) {
            u32 w = ((const u32*)&myRec)[i >> 1];
            u32 rec = (i & 1) ? (w >> 16) : (w & 0xFFFFu);
            int pos = atomicAdd(&sCnt[rec >> 7], 1);
            sIdx[pos] = (u16)(rec & 127u);
        }
    }
    __syncthreads();                             // sort done; embed buf0 drained

    // ---- embed: hG = f16(x @ W_emb + b_emb), A from global x ----
    {
#pragma unroll
        for (int nt = 0; nt < 8; ++nt) {
            float bv = b_emb[nt * 16 + mm];
            acc[nt] = (f32x4){bv, bv, bv, bv};
        }
        f16x8 AE[2];
#pragma unroll
        for (int ks = 0; ks < 2; ++ks) {         // k = ks*32 + qd*8 + 0..7
            const float* xp = &x[(size_t)(row0g + strip + mm) * FIN + ks * 32 + qd * 8];
            float4 a = *(const float4*)xp;
            float4 b = *(const float4*)(xp + 4);
            union { u32 w[4]; f16x8 v; } o;
            o.w[0] = (u32)f16b(a.x) | ((u32)f16b(a.y) << 16);
            o.w[1] = (u32)f16b(a.z) | ((u32)f16b(a.w) << 16);
            o.w[2] = (u32)f16b(b.x) | ((u32)f16b(b.y) << 16);
            o.w[3] = (u32)f16b(b.z) | ((u32)f16b(b.w) << 16);
            AE[ks] = o.v;
        }
        stage(0, 1);                             // L0 mat0 half0 -> buf1
        mfma_half(0, AE[0], AE[1]);
#pragma unroll
        for (int nt = 0; nt < 8; ++nt)           // write h0 rows into hG (no relu)
#pragma unroll
            for (int r = 0; r < 4; ++r)
                hG[(strip + qd * 4 + r) * HSTR + nt * 16 + mm] =
                    f16b(acc[nt][r]);
        __syncthreads();                         // hG visible; buf1 DMA drained
    }

    // ---- two layers x 5 matrices, 2 half-steps each ----
    for (int L = 0; L < 2; ++L) {
        const float* bl = bias + L * DD;
#pragma unroll
        for (int i = 0; i < 8; ++i) acc[i] = (f32x4){0.f, 0.f, 0.f, 0.f};

        f16x8 AH[4];
#pragma unroll
        for (int ks = 0; ks < 4; ++ks)           // root A direct from hG
            AH[ks] = *(const f16x8*)&hG[(strip + mm) * HSTR + ks * 32 + qd * 8];

        for (int m = 0; m < 5; ++m) {
#pragma unroll
            for (int h = 0; h < 2; ++h) {
                int s = L * 10 + m * 2 + h;
                if (s + 1 < 20) stage(s + 1, s & 1);
                mfma_half((s + 1) & 1, AH[h * 2], AH[h * 2 + 1]);
                __syncthreads();                 // next buf drained; this buf free
            }
            if (m < 4) gather(m, AH);            // next mat's A, in-register
        }

        if (L == 0) {
            // h1 -> hG (all hG readers done: root-A + gathers precede mat4 barriers)
#pragma unroll
            for (int nt = 0; nt < 8; ++nt) {
                float bv = bl[nt * 16 + mm];
#pragma unroll
                for (int r = 0; r < 4; ++r)
                    hG[(strip + qd * 4 + r) * HSTR + nt * 16 + mm] =
                        f16b(fmaxf(acc[nt][r] + bv, 0.f));
            }
            __syncthreads();                     // h1 visible to all waves
        } else {
            // max-pool: per-wave column max -> LDS (red overlays dead sIdx) -> store
            float* red = (float*)sIdx;
#pragma unroll
            for (int nt = 0; nt < 8; ++nt) {
                float bv = bl[nt * 16 + mm];
                float vv = fmaxf(fmaxf(acc[nt][0], acc[nt][1]),
                                 fmaxf(acc[nt][2], acc[nt][3])) + bv;
                vv = fmaxf(vv, 0.f);             // relu(max) == max(relu)
                vv = fmaxf(vv, __shfl_xor(vv, 16));
                vv = fmaxf(vv, __shfl_xor(vv, 32));
                if (lane < 16) red[wave * 128 + nt * 16 + mm] = vv;
            }
            __syncthreads();
            if (tid < 128) {
                float mx = red[tid];
#pragma unroll
                for (int w = 1; w < 8; ++w) mx = fmaxf(mx, red[w * 128 + tid]);
                outF[gr * DD + tid] = mx;
            }
        }
    }
}

// ---------------- launch ----------------

extern "C" void kernel_launch(void* const* d_in, const int* in_sizes, int n_in,
                              void* d_out, int out_size, void* d_ws, size_t ws_size,
                              hipStream_t stream) {
    const float* x      = (const float*)d_in[0];
    const int*   ei     = (const int*)  d_in[1];
    const int*   ea     = (const int*)  d_in[2];
    const float* W_emb  = (const float*)d_in[3];
    const float* b_emb  = (const float*)d_in[4];
    const float* W_root = (const float*)d_in[5];
    const float* W_rel  = (const float*)d_in[6];
    const float* bias   = (const float*)d_in[7];
    float* out = (float*)d_out;

    char* p = (char*)d_ws;
    u32* bcur   = (u32*)p; p += (size_t)512 * BPAD * 4;             // padded cursors (memset 0)
    u16* binned = (u16*)p; p += (size_t)GG * SLC * 2;               // 4.19 MB static slices
    u16* wtH    = (u16*)p; p += (size_t)(10 * 16384 + 8192) * 2;    // 0.35 MB (+wtE)

    (void)hipMemsetAsync(bcur, 0, (size_t)512 * BPAD * 4, stream);

    k_front<<<426, 256, 0, stream>>>(ei, ea, bcur, binned,
                                     W_root, W_rel, W_emb, wtH);
    k_fused<<<GG, 512, 0, stream>>>(x, b_emb, out, wtH, bias, binned, bcur);
}